// Round 1
// 180.099 us; speedup vs baseline: 1.0023x; 1.0023x over previous
//
#include <hip/hip_runtime.h>
#include <math.h>

#define Bn 2
#define Hn 8
#define Nn 256
#define Dn 64
#define BH 16
#define SCALER 0.125f

typedef _Float16 half8 __attribute__((ext_vector_type(8)));
typedef _Float16 half4 __attribute__((ext_vector_type(4)));
typedef float floatx4 __attribute__((ext_vector_type(4)));

__device__ __forceinline__ void split_f32(float v, _Float16& h, _Float16& l) {
    h = (_Float16)v;
    l = (_Float16)(v - (float)h);
}

__device__ __forceinline__ void split8(const float4& v0, const float4& v1,
                                       half8& h, half8& l) {
    const float vv[8] = {v0.x, v0.y, v0.z, v0.w, v1.x, v1.y, v1.z, v1.w};
    #pragma unroll
    for (int e = 0; e < 8; ++e) {
        _Float16 hh, ll;
        split_f32(vv[e], hh, ll);
        h[e] = hh; l[e] = ll;
    }
}

__device__ __forceinline__ void gload_lds16(const float* g, void* lds_base) {
    __builtin_amdgcn_global_load_lds(
        (const __attribute__((address_space(1))) unsigned int*)g,
        (__attribute__((address_space(3))) unsigned int*)lds_base, 16, 0, 0);
}

// ---------------------------------------------------------------------------
// Fused split of x (blocks 0..255) and w (blocks 256..1535) to f16 hi/lo.
// ---------------------------------------------------------------------------
__global__ __launch_bounds__(256) void split2_kernel(
    const float* __restrict__ x, const float* __restrict__ w,
    _Float16* __restrict__ xh, _Float16* __restrict__ xl,
    _Float16* __restrict__ wh, _Float16* __restrict__ wl) {
    const int b = blockIdx.x;
    const float* src;
    _Float16 *hp, *lp;
    int idx;
    if (b < 256) {
        idx = (b * 256 + threadIdx.x) * 4;
        src = x; hp = xh; lp = xl;
    } else {
        idx = ((b - 256) * 256 + threadIdx.x) * 4;
        src = w; hp = wh; lp = wl;
    }
    const float4 v = *(const float4*)(src + idx);
    half4 hh, ll;
    _Float16 a2, b2;
    split_f32(v.x, a2, b2); hh[0] = a2; ll[0] = b2;
    split_f32(v.y, a2, b2); hh[1] = a2; ll[1] = b2;
    split_f32(v.z, a2, b2); hh[2] = a2; ll[2] = b2;
    split_f32(v.w, a2, b2); hh[3] = a2; ll[3] = b2;
    *(half4*)(hp + idx) = hh;
    *(half4*)(lp + idx) = ll;
}

// ---------------------------------------------------------------------------
// Projection, pre-split inputs, pure loads. Tile 64m x 64r, grid (8, 40).
// (320 blocks: better CU coverage than the 64x128 / 160-block variant;
//  chain-time by subtraction: ~53 us vs ~61 us.)
// ---------------------------------------------------------------------------
__global__ __launch_bounds__(256) void proj_mfma(
    const _Float16* __restrict__ xh, const _Float16* __restrict__ xl,
    const _Float16* __restrict__ wh, const _Float16* __restrict__ wl,
    float* __restrict__ P32) {
    const int m0 = blockIdx.x * 64;
    const int r0 = blockIdx.y * 64;
    const int t = threadIdx.x;
    const int w = t >> 6, l = t & 63;
    const int lr = l & 15, kk8 = (l >> 4) * 8;

    floatx4 acc[4];
    #pragma unroll
    for (int ni = 0; ni < 4; ++ni) acc[ni] = (floatx4){0.f, 0.f, 0.f, 0.f};

    const int arow = m0 + w * 16 + lr;
    for (int kt = 0; kt < 16; ++kt) {
        const int k0 = kt * 32 + kk8;
        const half8 ah = *(const half8*)(xh + arow * 512 + k0);
        const half8 al = *(const half8*)(xl + arow * 512 + k0);
        half8 bhv[4], blv[4];
        #pragma unroll
        for (int ni = 0; ni < 4; ++ni) {
            const int wr = r0 + ni * 16 + lr;
            bhv[ni] = *(const half8*)(wh + wr * 512 + k0);
            blv[ni] = *(const half8*)(wl + wr * 512 + k0);
        }
        #pragma unroll
        for (int ni = 0; ni < 4; ++ni)
            acc[ni] = __builtin_amdgcn_mfma_f32_16x16x32_f16(ah, bhv[ni], acc[ni], 0, 0, 0);
        #pragma unroll
        for (int ni = 0; ni < 4; ++ni)
            acc[ni] = __builtin_amdgcn_mfma_f32_16x16x32_f16(ah, blv[ni], acc[ni], 0, 0, 0);
        #pragma unroll
        for (int ni = 0; ni < 4; ++ni)
            acc[ni] = __builtin_amdgcn_mfma_f32_16x16x32_f16(al, bhv[ni], acc[ni], 0, 0, 0);
    }
    const int rbase = (l >> 4) * 4;
    #pragma unroll
    for (int ni = 0; ni < 4; ++ni) {
        const int rcol = r0 + ni * 16 + lr;
        const int s = rcol >> 9, h = (rcol >> 6) & 7, d = rcol & 63;
        #pragma unroll
        for (int r = 0; r < 4; ++r) {
            const int m = m0 + w * 16 + rbase + r;
            const int b = m >> 8, n = m & 255;
            P32[(((s * 2 + b) * 8 + h) * 256 + n) * 64 + d] = acc[ni][r];
        }
    }
}

// ---------------------------------------------------------------------------
// Scores + fused exp + vkT. Stabilization shifts dropped (cancel exactly).
// ---------------------------------------------------------------------------
__global__ __launch_bounds__(256) void score_vkt(
    const float* __restrict__ P32,
    _Float16* __restrict__ Xsh, _Float16* __restrict__ Xsl,
    float* __restrict__ Yt, float* __restrict__ Z, float* __restrict__ vkT) {
    const int bh = blockIdx.x, mat = blockIdx.y;
    const int t = threadIdx.x;
    if (mat == 3) {
        const int idx0 = blockIdx.z * 2048 + t * 8;
        const int d = idx0 >> 8, k0 = idx0 & 255;
        const float* src = P32 + (4 * 16 + bh) * 16384;
        float4 o0, o1;
        o0.x = src[(k0 + 0) * 64 + d]; o0.y = src[(k0 + 1) * 64 + d];
        o0.z = src[(k0 + 2) * 64 + d]; o0.w = src[(k0 + 3) * 64 + d];
        o1.x = src[(k0 + 4) * 64 + d]; o1.y = src[(k0 + 5) * 64 + d];
        o1.z = src[(k0 + 6) * 64 + d]; o1.w = src[(k0 + 7) * 64 + d];
        *(float4*)(vkT + (bh * 64 + d) * 256 + k0) = o0;
        *(float4*)(vkT + (bh * 64 + d) * 256 + k0 + 4) = o1;
        return;
    }
    const int i0 = (blockIdx.z >> 2) * 128;
    const int j0 = (blockIdx.z & 3) * 64;
    const int w = t >> 6, l = t & 63;
    const int lr = l & 15, kk8 = (l >> 4) * 8;
    const float* A;
    const float* Bm;
    if (mat == 0)      { A = P32 + (1 * 16 + bh) * 16384; Bm = P32 + (2 * 16 + bh) * 16384; }
    else if (mat == 1) { A = P32 + (0 * 16 + bh) * 16384; Bm = P32 + (2 * 16 + bh) * 16384; }
    else               { A = P32 + (0 * 16 + bh) * 16384; Bm = P32 + (1 * 16 + bh) * 16384; }

    floatx4 acc[2][4];
    #pragma unroll
    for (int mi = 0; mi < 2; ++mi)
        #pragma unroll
        for (int ni = 0; ni < 4; ++ni) acc[mi][ni] = (floatx4){0.f, 0.f, 0.f, 0.f};

    for (int kt = 0; kt < 2; ++kt) {
        const int k0 = kt * 32 + kk8;
        half8 ah[2], al[2], bh8[4], bl8[4];
        #pragma unroll
        for (int mi = 0; mi < 2; ++mi) {
            const int row = i0 + w * 32 + mi * 16 + lr;
            const float4 v0 = *(const float4*)(A + row * 64 + k0);
            const float4 v1 = *(const float4*)(A + row * 64 + k0 + 4);
            split8(v0, v1, ah[mi], al[mi]);
        }
        #pragma unroll
        for (int ni = 0; ni < 4; ++ni) {
            const int row = j0 + ni * 16 + lr;
            const float4 v0 = *(const float4*)(Bm + row * 64 + k0);
            const float4 v1 = *(const float4*)(Bm + row * 64 + k0 + 4);
            split8(v0, v1, bh8[ni], bl8[ni]);
        }
        #pragma unroll
        for (int mi = 0; mi < 2; ++mi)
            #pragma unroll
            for (int ni = 0; ni < 4; ++ni)
                acc[mi][ni] = __builtin_amdgcn_mfma_f32_16x16x32_f16(ah[mi], bh8[ni], acc[mi][ni], 0, 0, 0);
        #pragma unroll
        for (int mi = 0; mi < 2; ++mi)
            #pragma unroll
            for (int ni = 0; ni < 4; ++ni)
                acc[mi][ni] = __builtin_amdgcn_mfma_f32_16x16x32_f16(ah[mi], bl8[ni], acc[mi][ni], 0, 0, 0);
        #pragma unroll
        for (int mi = 0; mi < 2; ++mi)
            #pragma unroll
            for (int ni = 0; ni < 4; ++ni)
                acc[mi][ni] = __builtin_amdgcn_mfma_f32_16x16x32_f16(al[mi], bh8[ni], acc[mi][ni], 0, 0, 0);
    }
    const int rbase = (l >> 4) * 4;
    #pragma unroll
    for (int mi = 0; mi < 2; ++mi)
        #pragma unroll
        for (int ni = 0; ni < 4; ++ni)
            #pragma unroll
            for (int r = 0; r < 4; ++r) {
                const int row = i0 + w * 32 + mi * 16 + rbase + r;
                const int col = j0 + ni * 16 + lr;
                const float e = expf(acc[mi][ni][r] * SCALER);
                if (mat == 0) {
                    const int idx = (bh * 256 + row) * 256 + col;
                    _Float16 hh, ll; split_f32(e, hh, ll);
                    Xsh[idx] = hh; Xsl[idx] = ll;
                } else if (mat == 1) {
                    Yt[bh * 65536 + row * 256 + col] = e;
                } else {
                    Z[bh * 65536 + row * 256 + col] = e;
                }
            }
}

// ---------------------------------------------------------------------------
// Den. grid (16,16): bh x 16-row i-tile. 4 waves split 16 jt-groups.
// ---------------------------------------------------------------------------
__global__ __launch_bounds__(256) void den_mfma(
    const float* __restrict__ Yt, const _Float16* __restrict__ Xh,
    const _Float16* __restrict__ Xl, const float* __restrict__ Z,
    float* __restrict__ Den) {
    const int bh = blockIdx.x;
    const int ibase = blockIdx.y * 16;
    const int t = threadIdx.x;
    const int w = t >> 6, l = t & 63;
    const int lr = l & 15, ks = l >> 4, kk8 = ks * 8;
    const float* Ytp = Yt + bh * 65536;
    const _Float16* Xhp = Xh + bh * 65536;
    const _Float16* Xlp = Xl + bh * 65536;

    floatx4 acc[4];
    #pragma unroll
    for (int q = 0; q < 4; ++q) acc[q] = (floatx4){0.f, 0.f, 0.f, 0.f};

    for (int kt = 0; kt < 8; ++kt) {
        const int k0 = kt * 32 + kk8;
        half8 ah, al;
        {
            const float4 v0 = *(const float4*)(Ytp + (ibase + lr) * 256 + k0);
            const float4 v1 = *(const float4*)(Ytp + (ibase + lr) * 256 + k0 + 4);
            split8(v0, v1, ah, al);
        }
        half8 bh8[4], bl8[4];
        #pragma unroll
        for (int q = 0; q < 4; ++q) {
            const int jt = w * 4 + q;
            bh8[q] = *(const half8*)(Xhp + (jt * 16 + lr) * 256 + k0);
            bl8[q] = *(const half8*)(Xlp + (jt * 16 + lr) * 256 + k0);
        }
        #pragma unroll
        for (int q = 0; q < 4; ++q)
            acc[q] = __builtin_amdgcn_mfma_f32_16x16x32_f16(ah, bh8[q], acc[q], 0, 0, 0);
        #pragma unroll
        for (int q = 0; q < 4; ++q)
            acc[q] = __builtin_amdgcn_mfma_f32_16x16x32_f16(ah, bl8[q], acc[q], 0, 0, 0);
        #pragma unroll
        for (int q = 0; q < 4; ++q)
            acc[q] = __builtin_amdgcn_mfma_f32_16x16x32_f16(al, bh8[q], acc[q], 0, 0, 0);
    }
    __shared__ float redS[4][16];
    float dp[4] = {0.f, 0.f, 0.f, 0.f};
    const float* Zp = Z + (bh * 256 + ibase) * 256;
    #pragma unroll
    for (int q = 0; q < 4; ++q) {
        const int jt = w * 4 + q;
        #pragma unroll
        for (int r = 0; r < 4; ++r)
            dp[r] += acc[q][r] * Zp[(ks * 4 + r) * 256 + jt * 16 + lr];
    }
    #pragma unroll
    for (int r = 0; r < 4; ++r) {
        float s = dp[r];
        s += __shfl_xor(s, 1); s += __shfl_xor(s, 2);
        s += __shfl_xor(s, 4); s += __shfl_xor(s, 8);
        if (lr == 0) redS[w][ks * 4 + r] = s;
    }
    __syncthreads();
    if (t < 16)
        Den[bh * 256 + ibase + t] =
            redS[0][t] + redS[1][t] + redS[2][t] + redS[3][t] + 1e-9f;
}

// ---------------------------------------------------------------------------
// Main contraction (R7 structure). G=2 i-sharing; A direct-global register
// double-buffered; raw vk staged to LDS via global_load_lds (2 tiles ahead,
// counted vmcnt, raw s_barrier so in-flight loads survive the barrier).
// BSTORE: raw LDS -> *y -> split -> swizzled BhS/BlS.
// R8: redN aliased onto yiS (both 2048 B; yiS dead after last BSTORE, which
// is separated from first redN write by an s_barrier). LDS 55296 -> 53248 B
// => 3 workgroups/CU (was 2): occupancy 8 -> 12 waves/CU to cover the
// per-step barrier drain.
// ---------------------------------------------------------------------------
__global__ __launch_bounds__(256, 2) void attn_mfma(
    const _Float16* __restrict__ Xh, const _Float16* __restrict__ Xl,
    const float* __restrict__ Yt, const float* __restrict__ Z,
    const float* __restrict__ vkT, const float* __restrict__ P32,
    const float* __restrict__ Den, float* __restrict__ out) {
    const int id = (blockIdx.x & 7) * 256 + (blockIdx.x >> 3);  // XCD swizzle
    const int bh = id >> 7;
    const int i0 = (id & 127) * 2;
    const int t = threadIdx.x;
    const int w = t >> 6, l = t & 63;
    const int lr = l & 15, ks = l >> 4, kk8 = ks * 8;

    __shared__ float yiS[2][256], ziS[2][256];
    __shared__ float RAW[2][2048];                    // raw vk f32 tiles
    __shared__ _Float16 BhS[2][2][2048], BlS[2][2][2048];
    // redN aliases yiS (exact same 2048 B footprint). Safe: last yiS read is
    // in BSTORE(7), followed by lgkmcnt(0)+s_barrier before any wave reaches
    // the epilogue's redN writes. STAGE(8)/(9) tail DMAs land in RAW only.
    float (*redN)[2][64] = reinterpret_cast<float (*)[2][64]>(&yiS[0][0]);

    yiS[0][t] = Yt[(bh * 256 + i0) * 256 + t];
    yiS[1][t] = Yt[(bh * 256 + i0 + 1) * 256 + t];
    ziS[0][t] = Z[(bh * 256 + i0) * 256 + t];
    ziS[1][t] = Z[(bh * 256 + i0 + 1) * 256 + t];

    const _Float16* Xhp = Xh + bh * 65536;
    const _Float16* Xlp = Xl + bh * 65536;
    const float* vkp = vkT + bh * 16384;
    const float* vj = P32 + (3 * 16 + bh) * 16384;

    floatx4 acc[4][8];
    #pragma unroll
    for (int mi = 0; mi < 4; ++mi)
        #pragma unroll
        for (int ct = 0; ct < 8; ++ct) acc[mi][ct] = (floatx4){0.f, 0.f, 0.f, 0.f};

    const int bi = t >> 7;            // i within pair
    const int bd = (t >> 1) & 63;     // d row
    const int hf = t & 1;             // k-half (16 f32)
    const int bs2 = hf * 2;

    // ---- STAGE: raw vk tile kt -> RAW[kt&1] via global_load_lds
    auto STAGE = [&](int kt) {
        const int k0 = (kt & 7) * 32;
        const int buf = kt & 1;
        #pragma unroll
        for (int q = 0; q < 2; ++q) {
            const int u = q * 256 + t;
            const int g = u >> 7, ubd = (u & 127) >> 1, uhf = u & 1;
            const float* gp = vkp + ubd * 256 + k0 + uhf * 16 + g * 4;
            void* lp = (char*)&RAW[buf][0] + q * 4096 + w * 1024;  // wave-uniform
            gload_lds16(gp, lp);
        }
    };
    // ---- BSTORE: RAW[buf] -> *y -> split -> BhS/BlS[buf]
    auto BSTORE = [&](int kt) {
        const int buf = kt & 1;
        const float* yrow = &yiS[bi][(kt & 7) * 32 + bs2 * 8];
        float4 V[4];
        #pragma unroll
        for (int g = 0; g < 4; ++g)
            V[g] = *(float4*)&RAW[buf][g * 512 + bd * 8 + hf * 4];
        #pragma unroll
        for (int g = 0; g < 2; ++g) {
            const float4 y0 = *(const float4*)(yrow + g * 8);
            const float4 y1 = *(const float4*)(yrow + g * 8 + 4);
            const float4 v0 = V[g * 2], v1 = V[g * 2 + 1];
            const float pv[8] = {v0.x * y0.x, v0.y * y0.y, v0.z * y0.z, v0.w * y0.w,
                                 v1.x * y1.x, v1.y * y1.y, v1.z * y1.z, v1.w * y1.w};
            half8 hv, lv;
            #pragma unroll
            for (int e = 0; e < 8; ++e) {
                _Float16 hh, ll;
                split_f32(pv[e], hh, ll);
                hv[e] = hh; lv[e] = ll;
            }
            const int off = ((bd * 4 + bs2 + g) ^ ((bd >> 1) & 7)) * 8;
            *(half8*)&BhS[buf][bi][off] = hv;
            *(half8*)&BlS[buf][bi][off] = lv;
        }
    };
    auto LOADA = [&](half8* AH, half8* AL, int kt) {
        const int k0 = (kt & 7) * 32 + kk8;
        #pragma unroll
        for (int mi = 0; mi < 4; ++mi) {
            const int row = w * 64 + mi * 16 + lr;
            AH[mi] = *(const half8*)(Xhp + row * 256 + k0);
            AL[mi] = *(const half8*)(Xlp + row * 256 + k0);
        }
    };
    auto MFMA_STEP = [&](half8* AH, half8* AL, int buf) {
        __builtin_amdgcn_s_setprio(1);
        #pragma unroll
        for (int ct = 0; ct < 8; ++ct) {
            const int ii = ct >> 2;
            const int dd = (ct & 3) * 16 + lr;
            const int off = ((dd * 4 + ks) ^ ((dd >> 1) & 7)) * 8;
            const half8 bhf = *(const half8*)&BhS[buf][ii][off];
            const half8 blf = *(const half8*)&BlS[buf][ii][off];
            #pragma unroll
            for (int mi = 0; mi < 4; ++mi)
                acc[mi][ct] = __builtin_amdgcn_mfma_f32_16x16x32_f16(AH[mi], bhf, acc[mi][ct], 0, 0, 0);
            #pragma unroll
            for (int mi = 0; mi < 4; ++mi)
                acc[mi][ct] = __builtin_amdgcn_mfma_f32_16x16x32_f16(AH[mi], blf, acc[mi][ct], 0, 0, 0);
            #pragma unroll
            for (int mi = 0; mi < 4; ++mi)
                acc[mi][ct] = __builtin_amdgcn_mfma_f32_16x16x32_f16(AL[mi], bhf, acc[mi][ct], 0, 0, 0);
        }
        __builtin_amdgcn_s_setprio(0);
    };

    half8 A0h[4], A0l[4], A1h[4], A1l[4];

    // ---- prologue: STAGE(0), STAGE(1), A(0); build B(0)
    STAGE(0);
    STAGE(1);
    LOADA(A0h, A0l, 0);
    asm volatile("s_waitcnt vmcnt(10)" ::: "memory");   // STAGE(0) landed
    __builtin_amdgcn_sched_barrier(0);
    asm volatile("s_waitcnt lgkmcnt(0)" ::: "memory");  // yiS/ziS visible
    __builtin_amdgcn_s_barrier();
    BSTORE(0);
    asm volatile("s_waitcnt lgkmcnt(0)" ::: "memory");
    __builtin_amdgcn_s_barrier();

    // ---- main loop: per step: STAGE(kt+2) | LOADA(kt+1) | MFMA(kt) |
    //      vmcnt(18) | BSTORE(kt+1) | barrier
    #pragma unroll 1
    for (int kq = 0; kq < 4; ++kq) {
        const int kt = kq * 2;
        // even step (cur buf 0)
        STAGE(kt + 2);
        LOADA(A1h, A1l, kt + 1);
        MFMA_STEP(A0h, A0l, 0);
        asm volatile("s_waitcnt vmcnt(18)" ::: "memory");
        __builtin_amdgcn_sched_barrier(0);
        BSTORE(kt + 1);
        asm volatile("s_waitcnt lgkmcnt(0)" ::: "memory");
        __builtin_amdgcn_s_barrier();
        // odd step (cur buf 1)
        STAGE(kt + 3);
        LOADA(A0h, A0l, kt + 2);
        MFMA_STEP(A1h, A1l, 1);
        if (kq < 3) {
            asm volatile("s_waitcnt vmcnt(18)" ::: "memory");
            __builtin_amdgcn_sched_barrier(0);
            BSTORE(kt + 2);
            asm volatile("s_waitcnt lgkmcnt(0)" ::: "memory");
            __builtin_amdgcn_s_barrier();
        }
    }

    // ---- epilogue
    float z0[16], z1[16];
    #pragma unroll
    for (int mi = 0; mi < 4; ++mi)
        #pragma unroll
        for (int r = 0; r < 4; ++r) {
            const int j = w * 64 + mi * 16 + ks * 4 + r;
            z0[mi * 4 + r] = ziS[0][j];
            z1[mi * 4 + r] = ziS[1][j];
        }
    #pragma unroll
    for (int dt = 0; dt < 4; ++dt) {
        float n0 = 0.f, n1 = 0.f;
        #pragma unroll
        for (int mi = 0; mi < 4; ++mi)
            #pragma unroll
            for (int r = 0; r < 4; ++r) {
                const int j = w * 64 + mi * 16 + ks * 4 + r;
                const float v = vj[j * 64 + dt * 16 + lr];
                n0 += acc[mi][dt][r] * z0[mi * 4 + r] * v;
                n1 += acc[mi][dt + 4][r] * z1[mi * 4 + r] * v;
            }
        n0 += __shfl_xor(n0, 16); n0 += __shfl_xor(n0, 32);
        n1 += __shfl_xor(n1, 16); n1 += __shfl_xor(n1, 32);
        if (l < 16) {
            redN[w][0][dt * 16 + l] = n0;
            redN[w][1][dt * 16 + l] = n1;
        }
    }
    __syncthreads();
    if (t < 128) {
        const int ih = t >> 6, d = t & 63;
        const float num = redN[0][ih][d] + redN[1][ih][d] +
                          redN[2][ih][d] + redN[3][ih][d];
        const int i = i0 + ih;
        const float den = Den[bh * 256 + i];
        out[((bh >> 3) * 256 + i) * 512 + (bh & 7) * 64 + d] = num / den;
    }
}

extern "C" void kernel_launch(void* const* d_in, const int* in_sizes, int n_in,
                              void* d_out, int out_size, void* d_ws, size_t ws_size,
                              hipStream_t stream) {
    const float* x = (const float*)d_in[0];
    const float* w = (const float*)d_in[1];
    float* out = (float*)d_out;

    float* ws = (float*)d_ws;
    float* P32 = ws;                                    // 1,310,720 f32
    float* U = ws + 1310720;
    // epoch A (proj inputs, dead after proj):
    _Float16* xh = (_Float16*)U;
    _Float16* xl = xh + 262144;
    _Float16* wh = xl + 262144;
    _Float16* wl = wh + 1310720;
    // epoch B (score onward):
    _Float16* Xsh = (_Float16*)U;                       // 1,048,576 h
    _Float16* Xsl = Xsh + 1048576;
    float* Yt = U + 1048576;                            // 1,048,576 f32
    float* Z = Yt + 1048576;                            // 1,048,576 f32
    float* vkT = Z + 1048576;                           // 262,144 f32
    float* Den = vkT + 262144;                          // 4,096 f32

    split2_kernel<<<1536, 256, 0, stream>>>(x, w, xh, xl, wh, wl);
    proj_mfma<<<dim3(8, 40), 256, 0, stream>>>(xh, xl, wh, wl, P32);
    score_vkt<<<dim3(16, 4, 8), 256, 0, stream>>>(P32, Xsh, Xsl, Yt, Z, vkT);
    den_mfma<<<dim3(16, 16), 256, 0, stream>>>(Yt, Xsh, Xsl, Z, Den);
    attn_mfma<<<2048, 256, 0, stream>>>(Xsh, Xsl, Yt, Z, vkT, P32, Den, out);
}